// Round 1
// baseline (2563.904 us; speedup 1.0000x reference)
//
#include <hip/hip_runtime.h>

// TxGNN: 2-layer edge-conditioned SAGE conv on MI355X.
// Factorization: cat(x_src, ea) @ Wm == x_src@Wm_top + ea@Wm_bot.
// Per layer: (1) node GEMM xw = x@Wm_top, (2) fused edge GEMM ea@Wm_bot
// + gather xw[src] + bias + relu + atomic scatter-add to aggr[dst],
// (3) update GEMM h = relu(cat(aggr,x)@Wa + ba).

constexpr int N_NODES = 50000;
constexpr int N_EDGES = 640000;
constexpr int DF = 128;   // node feature dim (in = hid = out)
constexpr int DE = 64;    // edge feature dim

// ---------------------------------------------------------------------------
// Generic row GEMM: C[i] = act( cat(A1[i], A2[i]) @ W + bias ), BN = 128 wide.
// A1: [n, K1], A2: [n, K2] (K2 may be 0 -> A2 ignored), W: [K1+K2, 128].
// BM=64 rows/block, BK=32, 256 threads, 8x4 outputs/thread.
// ---------------------------------------------------------------------------
template<int K1, int K2, bool RELU, bool BIAS>
__global__ __launch_bounds__(256)
void gemm_rows(const float* __restrict__ A1,
               const float* __restrict__ A2,
               const float* __restrict__ W,
               const float* __restrict__ bias,
               float* __restrict__ C, int n)
{
    constexpr int K = K1 + K2;
    constexpr int BM = 64, BN = 128, BK = 32;
    __shared__ float As[BK][BM];   // A tile, transposed: As[k][row]
    __shared__ float Ws[BK][BN];

    const int r0 = blockIdx.x * BM;
    const int t  = threadIdx.x;
    const int tx = t & 31;         // col group: cols tx*4 .. tx*4+3
    const int ty = t >> 5;         // row group: rows ty*8 .. ty*8+7

    float acc[8][4];
    #pragma unroll
    for (int r = 0; r < 8; ++r)
        #pragma unroll
        for (int c = 0; c < 4; ++c) acc[r][c] = 0.f;

    // A-tile load mapping: thread -> (row rload, 8 consecutive k at koff)
    const int rload = t >> 2;              // 0..63
    const int koff  = (t & 3) * 8;         // 0,8,16,24
    int row = r0 + rload; if (row >= n) row = n - 1;   // clamp (tail-safe)
    const float* a1 = A1 + (size_t)row * K1;
    const float* a2 = (K2 > 0) ? (A2 + (size_t)row * K2) : nullptr;

    for (int k0 = 0; k0 < K; k0 += BK) {
        #pragma unroll
        for (int u = 0; u < 8; u += 4) {
            const int k = k0 + koff + u;
            float4 v;
            if (K2 == 0 || k < K1) v = *(const float4*)(a1 + k);
            else                   v = *(const float4*)(a2 + (k - K1));
            As[koff + u + 0][rload] = v.x;
            As[koff + u + 1][rload] = v.y;
            As[koff + u + 2][rload] = v.z;
            As[koff + u + 3][rload] = v.w;
        }
        #pragma unroll
        for (int u = 0; u < 4; ++u) {
            const int kk = u * 8 + ty;     // 0..31
            *(float4*)&Ws[kk][tx * 4] =
                *(const float4*)(W + (size_t)(k0 + kk) * BN + tx * 4);
        }
        __syncthreads();
        #pragma unroll
        for (int k = 0; k < BK; ++k) {
            float a[8];
            *(float4*)&a[0] = *(const float4*)&As[k][ty * 8];
            *(float4*)&a[4] = *(const float4*)&As[k][ty * 8 + 4];
            float w[4];
            *(float4*)w = *(const float4*)&Ws[k][tx * 4];
            #pragma unroll
            for (int r = 0; r < 8; ++r)
                #pragma unroll
                for (int c = 0; c < 4; ++c)
                    acc[r][c] = fmaf(a[r], w[c], acc[r][c]);
        }
        __syncthreads();
    }

    float bv[4] = {0.f, 0.f, 0.f, 0.f};
    if (BIAS) *(float4*)bv = *(const float4*)(bias + tx * 4);
    #pragma unroll
    for (int r = 0; r < 8; ++r) {
        const int rr = r0 + ty * 8 + r;
        if (rr < n) {
            float4 o;
            float v0 = acc[r][0] + bv[0];
            float v1 = acc[r][1] + bv[1];
            float v2 = acc[r][2] + bv[2];
            float v3 = acc[r][3] + bv[3];
            if (RELU) {
                v0 = v0 > 0.f ? v0 : 0.f;
                v1 = v1 > 0.f ? v1 : 0.f;
                v2 = v2 > 0.f ? v2 : 0.f;
                v3 = v3 > 0.f ? v3 : 0.f;
            }
            o.x = v0; o.y = v1; o.z = v2; o.w = v3;
            *(float4*)(C + (size_t)rr * BN + tx * 4) = o;
        }
    }
}

// ---------------------------------------------------------------------------
// Edge message + scatter: for 64 edges/block,
//   m[e] = relu( xw[src[e]] + ea[e] @ Wbot + bias );  aggr[dst[e]] += m[e]
// ea: [E,64], Wbot: [64,128]. Same tile scheme, K=64.
// ---------------------------------------------------------------------------
__global__ __launch_bounds__(256)
void msg_scatter(const float* __restrict__ xw,    // [N,128] precomputed x@Wtop
                 const float* __restrict__ ea,    // [E,64]
                 const int*   __restrict__ src,
                 const int*   __restrict__ dst,
                 const float* __restrict__ Wbot,  // [64,128]
                 const float* __restrict__ bias,  // [128]
                 float* __restrict__ aggr)        // [N,128] (zeroed, atomic)
{
    constexpr int BM = 64, BN = 128, BK = 32, K = DE;
    __shared__ float As[BK][BM];
    __shared__ float Ws[BK][BN];

    const int e0 = blockIdx.x * BM;
    const int t  = threadIdx.x;
    const int tx = t & 31;
    const int ty = t >> 5;

    float acc[8][4];
    #pragma unroll
    for (int r = 0; r < 8; ++r)
        #pragma unroll
        for (int c = 0; c < 4; ++c) acc[r][c] = 0.f;

    const int eload = t >> 2;          // 0..63
    const int koff  = (t & 3) * 8;     // 0,8,16,24
    const float* arow = ea + (size_t)(e0 + eload) * K;

    for (int k0 = 0; k0 < K; k0 += BK) {
        #pragma unroll
        for (int u = 0; u < 8; u += 4) {
            const int k = k0 + koff + u;
            float4 v = *(const float4*)(arow + k);
            As[koff + u + 0][eload] = v.x;
            As[koff + u + 1][eload] = v.y;
            As[koff + u + 2][eload] = v.z;
            As[koff + u + 3][eload] = v.w;
        }
        #pragma unroll
        for (int u = 0; u < 4; ++u) {
            const int kk = u * 8 + ty;
            *(float4*)&Ws[kk][tx * 4] =
                *(const float4*)(Wbot + (size_t)(k0 + kk) * BN + tx * 4);
        }
        __syncthreads();
        #pragma unroll
        for (int k = 0; k < BK; ++k) {
            float a[8];
            *(float4*)&a[0] = *(const float4*)&As[k][ty * 8];
            *(float4*)&a[4] = *(const float4*)&As[k][ty * 8 + 4];
            float w[4];
            *(float4*)w = *(const float4*)&Ws[k][tx * 4];
            #pragma unroll
            for (int r = 0; r < 8; ++r)
                #pragma unroll
                for (int c = 0; c < 4; ++c)
                    acc[r][c] = fmaf(a[r], w[c], acc[r][c]);
        }
        __syncthreads();
    }

    float bv[4];
    *(float4*)bv = *(const float4*)(bias + tx * 4);
    #pragma unroll
    for (int r = 0; r < 8; ++r) {
        const int e = e0 + ty * 8 + r;
        const int s = src[e];
        const int d = dst[e];
        float xv[4];
        *(float4*)xv = *(const float4*)(xw + (size_t)s * BN + tx * 4);
        float* ap = aggr + (size_t)d * BN + tx * 4;
        #pragma unroll
        for (int c = 0; c < 4; ++c) {
            float v = acc[r][c] + xv[c] + bv[c];
            v = v > 0.f ? v : 0.f;
            atomicAdd(ap + c, v);
        }
    }
}

// ---------------------------------------------------------------------------
extern "C" void kernel_launch(void* const* d_in, const int* in_sizes, int n_in,
                              void* d_out, int out_size, void* d_ws, size_t ws_size,
                              hipStream_t stream) {
    const float* x    = (const float*)d_in[0];
    const int*   eidx = (const int*)  d_in[1];   // [2, E] (int32 per harness)
    const float* ea   = (const float*)d_in[2];
    const float* Wm1  = (const float*)d_in[3];   // [192,128]
    const float* bm1  = (const float*)d_in[4];
    const float* Wa1  = (const float*)d_in[5];   // [256,128]
    const float* ba1  = (const float*)d_in[6];
    const float* Wm2  = (const float*)d_in[7];   // [192,128]
    const float* bm2  = (const float*)d_in[8];
    const float* Wa2  = (const float*)d_in[9];   // [256,128]
    const float* ba2  = (const float*)d_in[10];
    float* out = (float*)d_out;

    const int* src = eidx;
    const int* dst = eidx + N_EDGES;

    const size_t nodeBuf = (size_t)N_NODES * DF;  // 6.4M floats = 25.6 MB
    float* xw   = (float*)d_ws;                   // x@Wm_top, reused as h@Wm2_top
    float* aggr = xw + nodeBuf;                   // scatter target (both layers)
    float* h    = aggr + nodeBuf;                 // layer-1 output

    const int gN = (N_NODES + 63) / 64;   // 782
    const int gE = N_EDGES / 64;          // 10000 (exact)
    dim3 blk(256);

    // ---- layer 1 ----
    hipMemsetAsync(aggr, 0, nodeBuf * sizeof(float), stream);
    gemm_rows<DF, 0, false, false><<<gN, blk, 0, stream>>>(
        x, nullptr, Wm1, nullptr, xw, N_NODES);                 // xw = x@Wm1_top
    msg_scatter<<<gE, blk, 0, stream>>>(
        xw, ea, src, dst, Wm1 + (size_t)DF * DF, bm1, aggr);
    gemm_rows<DF, DF, true, true><<<gN, blk, 0, stream>>>(
        aggr, x, Wa1, ba1, h, N_NODES);                         // h = relu(...)

    // ---- layer 2 ----
    hipMemsetAsync(aggr, 0, nodeBuf * sizeof(float), stream);
    gemm_rows<DF, 0, false, false><<<gN, blk, 0, stream>>>(
        h, nullptr, Wm2, nullptr, xw, N_NODES);                 // hw = h@Wm2_top
    msg_scatter<<<gE, blk, 0, stream>>>(
        xw, ea, src, dst, Wm2 + (size_t)DF * DF, bm2, aggr);
    gemm_rows<DF, DF, true, true><<<gN, blk, 0, stream>>>(
        aggr, h, Wa2, ba2, out, N_NODES);
}

// Round 2
// 1052.051 us; speedup vs baseline: 2.4371x; 2.4371x over previous
//
#include <hip/hip_runtime.h>

// TxGNN: 2-layer edge-conditioned SAGE conv on MI355X.
// R2: sort edges by dst (on-device CSR permutation, shared by both layers),
// run-compress the scatter so atomics drop ~10x. R1 showed msg_scatter was
// atomic-op-rate bound (VALUBusy 8.4%, HBM 18%, 1.31 GB atomic writeback).

constexpr int N_NODES = 50000;
constexpr int N_EDGES = 640000;
constexpr int DF = 128;   // node feature dim (in = hid = out)
constexpr int DE = 64;    // edge feature dim

__device__ __forceinline__ void fatomic(float* p, float v) {
#if defined(__AMDGCN__)
    unsafeAtomicAdd(p, v);   // HW global_atomic_add_f32 (gfx90a+)
#else
    atomicAdd(p, v);
#endif
}

// ---------------------------------------------------------------------------
// CSR build: histogram of dst -> exclusive scan -> permutation scatter.
// ---------------------------------------------------------------------------
__global__ __launch_bounds__(256)
void hist_kernel(const int* __restrict__ dst, int* __restrict__ hist) {
    int i = blockIdx.x * blockDim.x + threadIdx.x;
    if (i < N_EDGES) atomicAdd(&hist[dst[i]], 1);
}

__global__ __launch_bounds__(1024)
void scan_kernel(const int* __restrict__ hist, int* __restrict__ cursor) {
    __shared__ int buf[1024];
    __shared__ int carry;
    const int t = threadIdx.x;
    if (t == 0) carry = 0;
    __syncthreads();
    for (int base = 0; base < N_NODES; base += 1024) {
        const int i = base + t;
        int v = (i < N_NODES) ? hist[i] : 0;
        buf[t] = v;
        __syncthreads();
        #pragma unroll
        for (int off = 1; off < 1024; off <<= 1) {
            int x = (t >= off) ? buf[t - off] : 0;
            __syncthreads();
            buf[t] += x;
            __syncthreads();
        }
        if (i < N_NODES) cursor[i] = carry + buf[t] - v;   // exclusive
        __syncthreads();
        if (t == 0) carry += buf[1023];
        __syncthreads();
    }
}

__global__ __launch_bounds__(256)
void build_kernel(const int* __restrict__ src, const int* __restrict__ dst,
                  int* __restrict__ cursor,
                  int* __restrict__ perm, int* __restrict__ srcs,
                  int* __restrict__ dsts) {
    int e = blockIdx.x * blockDim.x + threadIdx.x;
    if (e < N_EDGES) {
        const int d = dst[e];
        const int pos = atomicAdd(&cursor[d], 1);
        perm[pos] = e;
        srcs[pos] = src[e];
        dsts[pos] = d;
    }
}

// ---------------------------------------------------------------------------
// Generic row GEMM: C[i] = act( cat(A1[i], A2[i]) @ W + bias ), BN = 128 wide.
// BM=64 rows/block, BK=32, 256 threads, 8x4 outputs/thread.
// ---------------------------------------------------------------------------
template<int K1, int K2, bool RELU, bool BIAS>
__global__ __launch_bounds__(256)
void gemm_rows(const float* __restrict__ A1,
               const float* __restrict__ A2,
               const float* __restrict__ W,
               const float* __restrict__ bias,
               float* __restrict__ C, int n)
{
    constexpr int K = K1 + K2;
    constexpr int BM = 64, BN = 128, BK = 32;
    __shared__ float As[BK][BM];
    __shared__ float Ws[BK][BN];

    const int r0 = blockIdx.x * BM;
    const int t  = threadIdx.x;
    const int tx = t & 31;
    const int ty = t >> 5;

    float acc[8][4];
    #pragma unroll
    for (int r = 0; r < 8; ++r)
        #pragma unroll
        for (int c = 0; c < 4; ++c) acc[r][c] = 0.f;

    const int rload = t >> 2;
    const int koff  = (t & 3) * 8;
    int row = r0 + rload; if (row >= n) row = n - 1;
    const float* a1 = A1 + (size_t)row * K1;
    const float* a2 = (K2 > 0) ? (A2 + (size_t)row * K2) : nullptr;

    for (int k0 = 0; k0 < K; k0 += BK) {
        #pragma unroll
        for (int u = 0; u < 8; u += 4) {
            const int k = k0 + koff + u;
            float4 v;
            if (K2 == 0 || k < K1) v = *(const float4*)(a1 + k);
            else                   v = *(const float4*)(a2 + (k - K1));
            As[koff + u + 0][rload] = v.x;
            As[koff + u + 1][rload] = v.y;
            As[koff + u + 2][rload] = v.z;
            As[koff + u + 3][rload] = v.w;
        }
        #pragma unroll
        for (int u = 0; u < 4; ++u) {
            const int kk = u * 8 + ty;
            *(float4*)&Ws[kk][tx * 4] =
                *(const float4*)(W + (size_t)(k0 + kk) * BN + tx * 4);
        }
        __syncthreads();
        #pragma unroll
        for (int k = 0; k < BK; ++k) {
            float a[8];
            *(float4*)&a[0] = *(const float4*)&As[k][ty * 8];
            *(float4*)&a[4] = *(const float4*)&As[k][ty * 8 + 4];
            float w[4];
            *(float4*)w = *(const float4*)&Ws[k][tx * 4];
            #pragma unroll
            for (int r = 0; r < 8; ++r)
                #pragma unroll
                for (int c = 0; c < 4; ++c)
                    acc[r][c] = fmaf(a[r], w[c], acc[r][c]);
        }
        __syncthreads();
    }

    float bv[4] = {0.f, 0.f, 0.f, 0.f};
    if (BIAS) *(float4*)bv = *(const float4*)(bias + tx * 4);
    #pragma unroll
    for (int r = 0; r < 8; ++r) {
        const int rr = r0 + ty * 8 + r;
        if (rr < n) {
            float4 o;
            float v0 = acc[r][0] + bv[0];
            float v1 = acc[r][1] + bv[1];
            float v2 = acc[r][2] + bv[2];
            float v3 = acc[r][3] + bv[3];
            if (RELU) {
                v0 = v0 > 0.f ? v0 : 0.f;
                v1 = v1 > 0.f ? v1 : 0.f;
                v2 = v2 > 0.f ? v2 : 0.f;
                v3 = v3 > 0.f ? v3 : 0.f;
            }
            o.x = v0; o.y = v1; o.z = v2; o.w = v3;
            *(float4*)(C + (size_t)rr * BN + tx * 4) = o;
        }
    }
}

// ---------------------------------------------------------------------------
// Edge message + sorted scatter. Block = 64 sorted edge positions.
//   m[p] = relu( xw[srcs[p]] + ea[perm[p]] @ Wbot + bias )
// Edges sorted by dst -> each thread's 8 consecutive positions form ~1.5
// runs of equal dst; accumulate runs in registers, one atomic flush per run.
// ---------------------------------------------------------------------------
__global__ __launch_bounds__(256)
void msg_scatter_sorted(const float* __restrict__ xw,
                        const float* __restrict__ ea,
                        const int*   __restrict__ perm,
                        const int*   __restrict__ srcs,
                        const int*   __restrict__ dsts,
                        const float* __restrict__ Wbot,   // [64,128]
                        const float* __restrict__ bias,   // [128]
                        float* __restrict__ aggr)         // [N,128] zeroed
{
    constexpr int BM = 64, BN = 128, BK = 32, K = DE;
    __shared__ float As[BK][BM];
    __shared__ float Ws[BK][BN];

    const int p0 = blockIdx.x * BM;
    const int t  = threadIdx.x;
    const int tx = t & 31;
    const int ty = t >> 5;

    float acc[8][4];
    #pragma unroll
    for (int r = 0; r < 8; ++r)
        #pragma unroll
        for (int c = 0; c < 4; ++c) acc[r][c] = 0.f;

    const int eload = t >> 2;
    const int koff  = (t & 3) * 8;
    const float* arow = ea + (size_t)perm[p0 + eload] * K;

    for (int k0 = 0; k0 < K; k0 += BK) {
        #pragma unroll
        for (int u = 0; u < 8; u += 4) {
            const int k = k0 + koff + u;
            float4 v = *(const float4*)(arow + k);
            As[koff + u + 0][eload] = v.x;
            As[koff + u + 1][eload] = v.y;
            As[koff + u + 2][eload] = v.z;
            As[koff + u + 3][eload] = v.w;
        }
        #pragma unroll
        for (int u = 0; u < 4; ++u) {
            const int kk = u * 8 + ty;
            *(float4*)&Ws[kk][tx * 4] =
                *(const float4*)(Wbot + (size_t)(k0 + kk) * BN + tx * 4);
        }
        __syncthreads();
        #pragma unroll
        for (int k = 0; k < BK; ++k) {
            float a[8];
            *(float4*)&a[0] = *(const float4*)&As[k][ty * 8];
            *(float4*)&a[4] = *(const float4*)&As[k][ty * 8 + 4];
            float w[4];
            *(float4*)w = *(const float4*)&Ws[k][tx * 4];
            #pragma unroll
            for (int r = 0; r < 8; ++r)
                #pragma unroll
                for (int c = 0; c < 4; ++c)
                    acc[r][c] = fmaf(a[r], w[c], acc[r][c]);
        }
        __syncthreads();
    }

    float bv[4];
    *(float4*)bv = *(const float4*)(bias + tx * 4);

    // Run-compressed scatter over this thread's 8 consecutive sorted edges.
    int run_d = -1;
    float run[4] = {0.f, 0.f, 0.f, 0.f};
    #pragma unroll
    for (int r = 0; r < 8; ++r) {
        const int p = p0 + ty * 8 + r;
        const int s = srcs[p];
        const int d = dsts[p];
        float xv[4];
        *(float4*)xv = *(const float4*)(xw + (size_t)s * BN + tx * 4);
        float v[4];
        #pragma unroll
        for (int c = 0; c < 4; ++c) {
            v[c] = acc[r][c] + xv[c] + bv[c];
            v[c] = v[c] > 0.f ? v[c] : 0.f;
        }
        if (d != run_d) {
            if (run_d >= 0) {
                float* ap = aggr + (size_t)run_d * BN + tx * 4;
                #pragma unroll
                for (int c = 0; c < 4; ++c) fatomic(ap + c, run[c]);
            }
            run_d = d;
            #pragma unroll
            for (int c = 0; c < 4; ++c) run[c] = v[c];
        } else {
            #pragma unroll
            for (int c = 0; c < 4; ++c) run[c] += v[c];
        }
    }
    {
        float* ap = aggr + (size_t)run_d * BN + tx * 4;
        #pragma unroll
        for (int c = 0; c < 4; ++c) fatomic(ap + c, run[c]);
    }
}

// ---------------------------------------------------------------------------
extern "C" void kernel_launch(void* const* d_in, const int* in_sizes, int n_in,
                              void* d_out, int out_size, void* d_ws, size_t ws_size,
                              hipStream_t stream) {
    const float* x    = (const float*)d_in[0];
    const int*   eidx = (const int*)  d_in[1];   // [2, E]
    const float* ea   = (const float*)d_in[2];
    const float* Wm1  = (const float*)d_in[3];
    const float* bm1  = (const float*)d_in[4];
    const float* Wa1  = (const float*)d_in[5];
    const float* ba1  = (const float*)d_in[6];
    const float* Wm2  = (const float*)d_in[7];
    const float* bm2  = (const float*)d_in[8];
    const float* Wa2  = (const float*)d_in[9];
    const float* ba2  = (const float*)d_in[10];
    float* out = (float*)d_out;

    const int* src = eidx;
    const int* dst = eidx + N_EDGES;

    const size_t nodeBuf = (size_t)N_NODES * DF;
    float* xw   = (float*)d_ws;
    float* aggr = xw + nodeBuf;
    float* h    = aggr + nodeBuf;
    int*   cursor = (int*)(h + nodeBuf);
    int*   perm   = cursor + N_NODES;
    int*   srcs   = perm + N_EDGES;
    int*   dsts   = srcs + N_EDGES;
    // total: 76.8 MB float + 8.0 MB int

    const int gN = (N_NODES + 63) / 64;   // 782
    const int gE = N_EDGES / 64;          // 10000
    dim3 blk(256);

    // ---- CSR permutation (shared by both layers) ----
    hipMemsetAsync(cursor, 0, N_NODES * sizeof(int), stream);
    hist_kernel<<<(N_EDGES + 255) / 256, blk, 0, stream>>>(dst, cursor);
    // scan reads cursor as hist in-place? No: need separate hist; reuse perm as hist copy.
    // Simpler: hist into dsts (scratch), scan dsts -> cursor.
    // (Re-do properly below.)
    hipMemsetAsync(dsts, 0, N_NODES * sizeof(int), stream);
    hist_kernel<<<(N_EDGES + 255) / 256, blk, 0, stream>>>(dst, dsts);
    scan_kernel<<<1, 1024, 0, stream>>>(dsts, cursor);
    build_kernel<<<(N_EDGES + 255) / 256, blk, 0, stream>>>(
        src, dst, cursor, perm, srcs, dsts);

    // ---- layer 1 ----
    hipMemsetAsync(aggr, 0, nodeBuf * sizeof(float), stream);
    gemm_rows<DF, 0, false, false><<<gN, blk, 0, stream>>>(
        x, nullptr, Wm1, nullptr, xw, N_NODES);
    msg_scatter_sorted<<<gE, blk, 0, stream>>>(
        xw, ea, perm, srcs, dsts, Wm1 + (size_t)DF * DF, bm1, aggr);
    gemm_rows<DF, DF, true, true><<<gN, blk, 0, stream>>>(
        aggr, x, Wa1, ba1, h, N_NODES);

    // ---- layer 2 ----
    hipMemsetAsync(aggr, 0, nodeBuf * sizeof(float), stream);
    gemm_rows<DF, 0, false, false><<<gN, blk, 0, stream>>>(
        h, nullptr, Wm2, nullptr, xw, N_NODES);
    msg_scatter_sorted<<<gE, blk, 0, stream>>>(
        xw, ea, perm, srcs, dsts, Wm2 + (size_t)DF * DF, bm2, aggr);
    gemm_rows<DF, DF, true, true><<<gN, blk, 0, stream>>>(
        aggr, h, Wa2, ba2, out, N_NODES);
}

// Round 4
// 917.384 us; speedup vs baseline: 2.7948x; 1.1468x over previous
//
#include <hip/hip_runtime.h>

// TxGNN R4: R3 (bf16 MFMA everywhere) with the B-tile staging bug fixed.
// R3 loaded only half of each 128x64 / 64-wide B tile into LDS (2 thr/row x
// 16 bf16 = 32 of 64 k) -> MFMA read uninitialized LDS -> absmax inf.
// Now each B thread loads 32 bf16 (4x uint4): full tile.

constexpr int N_NODES = 50000;
constexpr int N_EDGES = 640000;
constexpr int DF = 128;
constexpr int DE = 64;

typedef short bf16x8 __attribute__((ext_vector_type(8)));
typedef float f32x4 __attribute__((ext_vector_type(4)));

__device__ __forceinline__ void fatomic(float* p, float v) {
#if defined(__AMDGCN__)
    unsafeAtomicAdd(p, v);
#else
    atomicAdd(p, v);
#endif
}

__device__ __forceinline__ unsigned short f2bf(float f) {
    union { float f; unsigned u; } v; v.f = f;
    unsigned r = (v.u + 0x7FFFu + ((v.u >> 16) & 1u)) >> 16;
    return (unsigned short)r;
}

// ---------------------------------------------------------------------------
// Weight transpose+convert: W [K,128] f32 -> WT [128][K] bf16.
// ---------------------------------------------------------------------------
__global__ __launch_bounds__(256)
void wconv_kernel(const float* __restrict__ W, unsigned short* __restrict__ WT, int K) {
    int i = blockIdx.x * blockDim.x + threadIdx.x;
    if (i < K * 128) {
        int k = i >> 7, n = i & 127;
        WT[n * K + k] = f2bf(W[k * 128 + n]);
    }
}

// ---------------------------------------------------------------------------
// CSR build: histogram -> exclusive scan -> permutation scatter.
// ---------------------------------------------------------------------------
__global__ __launch_bounds__(256)
void hist_kernel(const int* __restrict__ dst, int* __restrict__ hist) {
    int i = blockIdx.x * blockDim.x + threadIdx.x;
    if (i < N_EDGES) atomicAdd(&hist[dst[i]], 1);
}

__global__ __launch_bounds__(1024)
void scan_kernel(const int* __restrict__ hist, int* __restrict__ cursor) {
    __shared__ int buf[1024];
    __shared__ int carry;
    const int t = threadIdx.x;
    if (t == 0) carry = 0;
    __syncthreads();
    for (int base = 0; base < N_NODES; base += 1024) {
        const int i = base + t;
        int v = (i < N_NODES) ? hist[i] : 0;
        buf[t] = v;
        __syncthreads();
        #pragma unroll
        for (int off = 1; off < 1024; off <<= 1) {
            int x = (t >= off) ? buf[t - off] : 0;
            __syncthreads();
            buf[t] += x;
            __syncthreads();
        }
        if (i < N_NODES) cursor[i] = carry + buf[t] - v;
        __syncthreads();
        if (t == 0) carry += buf[1023];
        __syncthreads();
    }
}

__global__ __launch_bounds__(256)
void build_kernel(const int* __restrict__ src, const int* __restrict__ dst,
                  int* __restrict__ cursor,
                  int* __restrict__ perm, int* __restrict__ srcs,
                  int* __restrict__ dsts) {
    int e = blockIdx.x * blockDim.x + threadIdx.x;
    if (e < N_EDGES) {
        const int d = dst[e];
        const int pos = atomicAdd(&cursor[d], 1);
        perm[pos] = e;
        srcs[pos] = src[e];
        dsts[pos] = d;
    }
}

// ---------------------------------------------------------------------------
// MFMA row GEMM: C[i,:] = act( cat(A1[i],A2[i]) @ W + bias ), N=128 wide.
// WT: [128][wstride] bf16 (transposed weights). BM=64, BK=64, 256 thr.
// Wave w computes rows w*16..+15 x all 128 cols (8 col-tiles, acc f32x4[8]).
// ---------------------------------------------------------------------------
template<int K1, int K2, bool RELU, bool BIAS>
__global__ __launch_bounds__(256)
void gemm_mfma(const float* __restrict__ A1,
               const float* __restrict__ A2,
               const unsigned short* __restrict__ WT, int wstride,
               const float* __restrict__ bias,
               float* __restrict__ C, int n)
{
    constexpr int K = K1 + K2;
    __shared__ unsigned short Asm[64][72];
    __shared__ unsigned short Bsm[128][72];

    const int r0   = blockIdx.x * 64;
    const int t    = threadIdx.x;
    const int wave = t >> 6;
    const int lane = t & 63;
    const int quad = lane >> 4;
    const int l15  = lane & 15;

    f32x4 acc[8];
    #pragma unroll
    for (int ct = 0; ct < 8; ++ct) acc[ct] = (f32x4)(0.f);

    const int arow  = t >> 2;            // 0..63
    const int acol0 = (t & 3) * 16;      // 0,16,32,48
    int arowg = r0 + arow; if (arowg >= n) arowg = n - 1;
    const int brow = t >> 1;             // 0..127
    const int bk   = (t & 1) * 32;       // 0,32

    for (int k0 = 0; k0 < K; k0 += 64) {
        // ---- A stage: 16 f32 -> 16 bf16 per thread (full 64x64 tile) ----
        {
            const int col = k0 + acol0;
            const float* sp = (K2 == 0 || col < K1)
                ? A1 + (size_t)arowg * K1 + col
                : A2 + (size_t)arowg * K2 + (col - K1);
            union { unsigned short us[16]; uint4 q[2]; } tmp;
            #pragma unroll
            for (int u = 0; u < 4; ++u) {
                float4 f = *(const float4*)(sp + u * 4);
                tmp.us[u * 4 + 0] = f2bf(f.x);
                tmp.us[u * 4 + 1] = f2bf(f.y);
                tmp.us[u * 4 + 2] = f2bf(f.z);
                tmp.us[u * 4 + 3] = f2bf(f.w);
            }
            *(uint4*)&Asm[arow][acol0]     = tmp.q[0];
            *(uint4*)&Asm[arow][acol0 + 8] = tmp.q[1];
        }
        // ---- B stage: 32 bf16 per thread (2 thr/row x 32 = full row) ----
        {
            const unsigned short* bp = WT + (size_t)brow * wstride + k0 + bk;
            uint4 b0 = *(const uint4*)(bp);
            uint4 b1 = *(const uint4*)(bp + 8);
            uint4 b2 = *(const uint4*)(bp + 16);
            uint4 b3 = *(const uint4*)(bp + 24);
            *(uint4*)&Bsm[brow][bk]      = b0;
            *(uint4*)&Bsm[brow][bk + 8]  = b1;
            *(uint4*)&Bsm[brow][bk + 16] = b2;
            *(uint4*)&Bsm[brow][bk + 24] = b3;
        }
        __syncthreads();
        #pragma unroll
        for (int kh = 0; kh < 2; ++kh) {
            bf16x8 a = *(const bf16x8*)&Asm[wave * 16 + l15][kh * 32 + quad * 8];
            #pragma unroll
            for (int ct = 0; ct < 8; ++ct) {
                bf16x8 b = *(const bf16x8*)&Bsm[ct * 16 + l15][kh * 32 + quad * 8];
                acc[ct] = __builtin_amdgcn_mfma_f32_16x16x32_bf16(a, b, acc[ct], 0, 0, 0);
            }
        }
        __syncthreads();
    }

    // ---- epilogue: D row = quad*4+reg, col = ct*16+l15 ----
    #pragma unroll
    for (int ct = 0; ct < 8; ++ct) {
        const int col = ct * 16 + l15;
        const float bval = BIAS ? bias[col] : 0.f;
        #pragma unroll
        for (int reg = 0; reg < 4; ++reg) {
            const int row = r0 + wave * 16 + quad * 4 + reg;
            if (row < n) {
                float v = acc[ct][reg] + bval;
                if (RELU) v = v > 0.f ? v : 0.f;
                C[(size_t)row * 128 + col] = v;
            }
        }
    }
}

// ---------------------------------------------------------------------------
// Edge message (MFMA) + sorted run-compressed scatter.
//   m[p] = relu( xw[srcs[p]] + ea[perm[p]] @ Wbot + bias ); aggr[dsts[p]] += m
// K=64 single stage. MFMA acc round-trips LDS to restore the R2 epilogue
// layout (thread owns cols tx*4..+3 of 8 consecutive sorted edges).
// ---------------------------------------------------------------------------
__global__ __launch_bounds__(256)
void msg_mfma(const float* __restrict__ xw,
              const float* __restrict__ ea,
              const int*   __restrict__ perm,
              const int*   __restrict__ srcs,
              const int*   __restrict__ dsts,
              const unsigned short* __restrict__ WbotT,  // [128][wstride]
              int wstride,
              const float* __restrict__ bias,
              float* __restrict__ aggr)
{
    __shared__ __align__(16) char smem[64 * 132 * 4];   // 33792 B
    unsigned short (*Asm)[72] = (unsigned short(*)[72])smem;            // 9216 B
    unsigned short (*Bsm)[72] = (unsigned short(*)[72])(smem + 9216);   // 18432 B
    float (*Ms)[132] = (float(*)[132])smem;                             // reuse

    const int p0   = blockIdx.x * 64;
    const int t    = threadIdx.x;
    const int wave = t >> 6;
    const int lane = t & 63;
    const int quad = lane >> 4;
    const int l15  = lane & 15;

    f32x4 acc[8];
    #pragma unroll
    for (int ct = 0; ct < 8; ++ct) acc[ct] = (f32x4)(0.f);

    // ---- A stage: gather ea rows via perm (full 64x64 tile) ----
    {
        const int arow  = t >> 2;
        const int acol0 = (t & 3) * 16;
        const int erow  = perm[p0 + arow];
        const float* sp = ea + (size_t)erow * DE + acol0;
        union { unsigned short us[16]; uint4 q[2]; } tmp;
        #pragma unroll
        for (int u = 0; u < 4; ++u) {
            float4 f = *(const float4*)(sp + u * 4);
            tmp.us[u * 4 + 0] = f2bf(f.x);
            tmp.us[u * 4 + 1] = f2bf(f.y);
            tmp.us[u * 4 + 2] = f2bf(f.z);
            tmp.us[u * 4 + 3] = f2bf(f.w);
        }
        *(uint4*)&Asm[arow][acol0]     = tmp.q[0];
        *(uint4*)&Asm[arow][acol0 + 8] = tmp.q[1];
    }
    // ---- B stage: 32 bf16 per thread (full 128x64 tile) ----
    {
        const int brow = t >> 1;
        const int bk   = (t & 1) * 32;
        const unsigned short* bp = WbotT + (size_t)brow * wstride + bk;
        uint4 b0 = *(const uint4*)(bp);
        uint4 b1 = *(const uint4*)(bp + 8);
        uint4 b2 = *(const uint4*)(bp + 16);
        uint4 b3 = *(const uint4*)(bp + 24);
        *(uint4*)&Bsm[brow][bk]      = b0;
        *(uint4*)&Bsm[brow][bk + 8]  = b1;
        *(uint4*)&Bsm[brow][bk + 16] = b2;
        *(uint4*)&Bsm[brow][bk + 24] = b3;
    }
    __syncthreads();
    #pragma unroll
    for (int kh = 0; kh < 2; ++kh) {
        bf16x8 a = *(const bf16x8*)&Asm[wave * 16 + l15][kh * 32 + quad * 8];
        #pragma unroll
        for (int ct = 0; ct < 8; ++ct) {
            bf16x8 b = *(const bf16x8*)&Bsm[ct * 16 + l15][kh * 32 + quad * 8];
            acc[ct] = __builtin_amdgcn_mfma_f32_16x16x32_bf16(a, b, acc[ct], 0, 0, 0);
        }
    }
    __syncthreads();

    // ---- acc -> Ms (edge-major fp32) ----
    #pragma unroll
    for (int ct = 0; ct < 8; ++ct)
        #pragma unroll
        for (int reg = 0; reg < 4; ++reg)
            Ms[wave * 16 + quad * 4 + reg][ct * 16 + l15] = acc[ct][reg];
    __syncthreads();

    // ---- R2 epilogue: run-compressed atomic scatter ----
    const int tx = t & 31;
    const int ty = t >> 5;
    float bv[4];
    *(float4*)bv = *(const float4*)(bias + tx * 4);

    int run_d = -1;
    float run[4] = {0.f, 0.f, 0.f, 0.f};
    #pragma unroll
    for (int r = 0; r < 8; ++r) {
        const int p = p0 + ty * 8 + r;
        const int s = srcs[p];
        const int d = dsts[p];
        float xv[4];
        *(float4*)xv = *(const float4*)(xw + (size_t)s * 128 + tx * 4);
        float m[4];
        *(float4*)m = *(const float4*)&Ms[ty * 8 + r][tx * 4];
        float v[4];
        #pragma unroll
        for (int c = 0; c < 4; ++c) {
            v[c] = m[c] + xv[c] + bv[c];
            v[c] = v[c] > 0.f ? v[c] : 0.f;
        }
        if (d != run_d) {
            if (run_d >= 0) {
                float* ap = aggr + (size_t)run_d * 128 + tx * 4;
                #pragma unroll
                for (int c = 0; c < 4; ++c) fatomic(ap + c, run[c]);
            }
            run_d = d;
            #pragma unroll
            for (int c = 0; c < 4; ++c) run[c] = v[c];
        } else {
            #pragma unroll
            for (int c = 0; c < 4; ++c) run[c] += v[c];
        }
    }
    {
        float* ap = aggr + (size_t)run_d * 128 + tx * 4;
        #pragma unroll
        for (int c = 0; c < 4; ++c) fatomic(ap + c, run[c]);
    }
}

// ---------------------------------------------------------------------------
extern "C" void kernel_launch(void* const* d_in, const int* in_sizes, int n_in,
                              void* d_out, int out_size, void* d_ws, size_t ws_size,
                              hipStream_t stream) {
    const float* x    = (const float*)d_in[0];
    const int*   eidx = (const int*)  d_in[1];
    const float* ea   = (const float*)d_in[2];
    const float* Wm1  = (const float*)d_in[3];
    const float* bm1  = (const float*)d_in[4];
    const float* Wa1  = (const float*)d_in[5];
    const float* ba1  = (const float*)d_in[6];
    const float* Wm2  = (const float*)d_in[7];
    const float* bm2  = (const float*)d_in[8];
    const float* Wa2  = (const float*)d_in[9];
    const float* ba2  = (const float*)d_in[10];
    float* out = (float*)d_out;

    const int* src = eidx;
    const int* dst = eidx + N_EDGES;

    const size_t nodeBuf = (size_t)N_NODES * DF;
    float* xw   = (float*)d_ws;
    float* aggr = xw + nodeBuf;
    float* h    = aggr + nodeBuf;
    int*   cursor = (int*)(h + nodeBuf);
    int*   perm   = cursor + N_NODES;
    int*   srcs   = perm + N_EDGES;
    int*   dsts   = srcs + N_EDGES;
    unsigned short* WmT1 = (unsigned short*)(dsts + N_EDGES);  // [128][192]
    unsigned short* WaT1 = WmT1 + 128 * 192;                   // [128][256]
    unsigned short* WmT2 = WaT1 + 128 * 256;
    unsigned short* WaT2 = WmT2 + 128 * 192;

    const int gN = (N_NODES + 63) / 64;   // 782
    const int gE = N_EDGES / 64;          // 10000
    dim3 blk(256);

    // ---- weights: transpose + bf16 ----
    wconv_kernel<<<(192 * 128 + 255) / 256, blk, 0, stream>>>(Wm1, WmT1, 192);
    wconv_kernel<<<(256 * 128 + 255) / 256, blk, 0, stream>>>(Wa1, WaT1, 256);
    wconv_kernel<<<(192 * 128 + 255) / 256, blk, 0, stream>>>(Wm2, WmT2, 192);
    wconv_kernel<<<(256 * 128 + 255) / 256, blk, 0, stream>>>(Wa2, WaT2, 256);

    // ---- CSR permutation (shared by both layers) ----
    hipMemsetAsync(cursor, 0, N_NODES * sizeof(int), stream);
    hipMemsetAsync(dsts, 0, N_NODES * sizeof(int), stream);
    hist_kernel<<<(N_EDGES + 255) / 256, blk, 0, stream>>>(dst, dsts);
    scan_kernel<<<1, 1024, 0, stream>>>(dsts, cursor);
    build_kernel<<<(N_EDGES + 255) / 256, blk, 0, stream>>>(
        src, dst, cursor, perm, srcs, dsts);

    // ---- layer 1 ----
    hipMemsetAsync(aggr, 0, nodeBuf * sizeof(float), stream);
    gemm_mfma<DF, 0, false, false><<<gN, blk, 0, stream>>>(
        x, nullptr, WmT1, 192, nullptr, xw, N_NODES);          // xw = x@Wm1_top
    msg_mfma<<<gE, blk, 0, stream>>>(
        xw, ea, perm, srcs, dsts, WmT1 + 128, 192, bm1, aggr); // WbotT: k-offset 128
    gemm_mfma<DF, DF, true, true><<<gN, blk, 0, stream>>>(
        aggr, x, WaT1, 256, ba1, h, N_NODES);

    // ---- layer 2 ----
    hipMemsetAsync(aggr, 0, nodeBuf * sizeof(float), stream);
    gemm_mfma<DF, 0, false, false><<<gN, blk, 0, stream>>>(
        h, nullptr, WmT2, 192, nullptr, xw, N_NODES);
    msg_mfma<<<gE, blk, 0, stream>>>(
        xw, ea, perm, srcs, dsts, WmT2 + 128, 192, bm2, aggr);
    gemm_mfma<DF, DF, true, true><<<gN, blk, 0, stream>>>(
        aggr, h, WaT2, 256, ba2, out, N_NODES);
}

// Round 5
// 844.976 us; speedup vs baseline: 3.0343x; 1.0857x over previous
//
#include <hip/hip_runtime.h>

// TxGNN R5: R4 + (1) xw/src/dst prefetch into registers before staging
// (msg epilogue was latency-bound: VALU 6.6%, HBM 26%, Mfma 1.7%),
// (2) complete-run plain stores instead of atomics, (3) 3-kernel scan
// replacing the serialized single-block scan.

constexpr int N_NODES = 50000;
constexpr int N_EDGES = 640000;
constexpr int DF = 128;
constexpr int DE = 64;

typedef short bf16x8 __attribute__((ext_vector_type(8)));
typedef float f32x4 __attribute__((ext_vector_type(4)));

__device__ __forceinline__ void fatomic(float* p, float v) {
#if defined(__AMDGCN__)
    unsafeAtomicAdd(p, v);
#else
    atomicAdd(p, v);
#endif
}

__device__ __forceinline__ unsigned short f2bf(float f) {
    union { float f; unsigned u; } v; v.f = f;
    unsigned r = (v.u + 0x7FFFu + ((v.u >> 16) & 1u)) >> 16;
    return (unsigned short)r;
}

// ---------------------------------------------------------------------------
// Weight transpose+convert: W [K,128] f32 -> WT [128][K] bf16.
// ---------------------------------------------------------------------------
__global__ __launch_bounds__(256)
void wconv_kernel(const float* __restrict__ W, unsigned short* __restrict__ WT, int K) {
    int i = blockIdx.x * blockDim.x + threadIdx.x;
    if (i < K * 128) {
        int k = i >> 7, n = i & 127;
        WT[n * K + k] = f2bf(W[k * 128 + n]);
    }
}

// ---------------------------------------------------------------------------
// CSR build: histogram -> 3-kernel exclusive scan -> permutation scatter.
// ---------------------------------------------------------------------------
__global__ __launch_bounds__(256)
void hist_kernel(const int* __restrict__ dst, int* __restrict__ hist) {
    int i = blockIdx.x * blockDim.x + threadIdx.x;
    if (i < N_EDGES) atomicAdd(&hist[dst[i]], 1);
}

__global__ __launch_bounds__(256)
void scan1_kernel(const int* __restrict__ hist, int* __restrict__ excl,
                  int* __restrict__ blksum, int n) {
    __shared__ int buf[256];
    const int t = threadIdx.x;
    const int i = blockIdx.x * 256 + t;
    int v = (i < n) ? hist[i] : 0;
    buf[t] = v;
    __syncthreads();
    #pragma unroll
    for (int off = 1; off < 256; off <<= 1) {
        int x = (t >= off) ? buf[t - off] : 0;
        __syncthreads();
        buf[t] += x;
        __syncthreads();
    }
    if (i < n) excl[i] = buf[t] - v;            // block-local exclusive
    if (t == 255) blksum[blockIdx.x] = buf[255];
}

__global__ __launch_bounds__(256)
void scan2_kernel(int* __restrict__ blksum, int nb) {
    __shared__ int buf[256];
    const int t = threadIdx.x;
    int v = (t < nb) ? blksum[t] : 0;
    buf[t] = v;
    __syncthreads();
    #pragma unroll
    for (int off = 1; off < 256; off <<= 1) {
        int x = (t >= off) ? buf[t - off] : 0;
        __syncthreads();
        buf[t] += x;
        __syncthreads();
    }
    if (t < nb) blksum[t] = buf[t] - v;         // exclusive block offsets
}

__global__ __launch_bounds__(256)
void scan3_kernel(int* __restrict__ excl, const int* __restrict__ blksum, int n) {
    const int i = blockIdx.x * 256 + threadIdx.x;
    if (i < n) excl[i] += blksum[blockIdx.x];
}

__global__ __launch_bounds__(256)
void build_kernel(const int* __restrict__ src, const int* __restrict__ dst,
                  int* __restrict__ cursor,
                  int* __restrict__ perm, int* __restrict__ srcs,
                  int* __restrict__ dsts) {
    int e = blockIdx.x * blockDim.x + threadIdx.x;
    if (e < N_EDGES) {
        const int d = dst[e];
        const int pos = atomicAdd(&cursor[d], 1);
        perm[pos] = e;
        srcs[pos] = src[e];
        dsts[pos] = d;
    }
}

// ---------------------------------------------------------------------------
// MFMA row GEMM: C[i,:] = act( cat(A1[i],A2[i]) @ W + bias ), N=128 wide.
// WT: [128][wstride] bf16 (transposed weights). BM=64, BK=64, 256 thr.
// ---------------------------------------------------------------------------
template<int K1, int K2, bool RELU, bool BIAS>
__global__ __launch_bounds__(256)
void gemm_mfma(const float* __restrict__ A1,
               const float* __restrict__ A2,
               const unsigned short* __restrict__ WT, int wstride,
               const float* __restrict__ bias,
               float* __restrict__ C, int n)
{
    constexpr int K = K1 + K2;
    __shared__ unsigned short Asm[64][72];
    __shared__ unsigned short Bsm[128][72];

    const int r0   = blockIdx.x * 64;
    const int t    = threadIdx.x;
    const int wave = t >> 6;
    const int lane = t & 63;
    const int quad = lane >> 4;
    const int l15  = lane & 15;

    f32x4 acc[8];
    #pragma unroll
    for (int ct = 0; ct < 8; ++ct) acc[ct] = (f32x4)(0.f);

    const int arow  = t >> 2;
    const int acol0 = (t & 3) * 16;
    int arowg = r0 + arow; if (arowg >= n) arowg = n - 1;
    const int brow = t >> 1;
    const int bk   = (t & 1) * 32;

    for (int k0 = 0; k0 < K; k0 += 64) {
        {
            const int col = k0 + acol0;
            const float* sp = (K2 == 0 || col < K1)
                ? A1 + (size_t)arowg * K1 + col
                : A2 + (size_t)arowg * K2 + (col - K1);
            union { unsigned short us[16]; uint4 q[2]; } tmp;
            #pragma unroll
            for (int u = 0; u < 4; ++u) {
                float4 f = *(const float4*)(sp + u * 4);
                tmp.us[u * 4 + 0] = f2bf(f.x);
                tmp.us[u * 4 + 1] = f2bf(f.y);
                tmp.us[u * 4 + 2] = f2bf(f.z);
                tmp.us[u * 4 + 3] = f2bf(f.w);
            }
            *(uint4*)&Asm[arow][acol0]     = tmp.q[0];
            *(uint4*)&Asm[arow][acol0 + 8] = tmp.q[1];
        }
        {
            const unsigned short* bp = WT + (size_t)brow * wstride + k0 + bk;
            uint4 b0 = *(const uint4*)(bp);
            uint4 b1 = *(const uint4*)(bp + 8);
            uint4 b2 = *(const uint4*)(bp + 16);
            uint4 b3 = *(const uint4*)(bp + 24);
            *(uint4*)&Bsm[brow][bk]      = b0;
            *(uint4*)&Bsm[brow][bk + 8]  = b1;
            *(uint4*)&Bsm[brow][bk + 16] = b2;
            *(uint4*)&Bsm[brow][bk + 24] = b3;
        }
        __syncthreads();
        #pragma unroll
        for (int kh = 0; kh < 2; ++kh) {
            bf16x8 a = *(const bf16x8*)&Asm[wave * 16 + l15][kh * 32 + quad * 8];
            #pragma unroll
            for (int ct = 0; ct < 8; ++ct) {
                bf16x8 b = *(const bf16x8*)&Bsm[ct * 16 + l15][kh * 32 + quad * 8];
                acc[ct] = __builtin_amdgcn_mfma_f32_16x16x32_bf16(a, b, acc[ct], 0, 0, 0);
            }
        }
        __syncthreads();
    }

    #pragma unroll
    for (int ct = 0; ct < 8; ++ct) {
        const int col = ct * 16 + l15;
        const float bval = BIAS ? bias[col] : 0.f;
        #pragma unroll
        for (int reg = 0; reg < 4; ++reg) {
            const int row = r0 + wave * 16 + quad * 4 + reg;
            if (row < n) {
                float v = acc[ct][reg] + bval;
                if (RELU) v = v > 0.f ? v : 0.f;
                C[(size_t)row * 128 + col] = v;
            }
        }
    }
}

// ---------------------------------------------------------------------------
// Edge message (MFMA) + sorted scatter with register prefetch.
//   m[p] = relu( xw[srcs[p]] + ea[perm[p]] @ Wbot + bias ); aggr[dsts[p]] += m
// srcs/dsts/xw prefetched into registers at block start (overlaps staging &
// MFMA). Runs fully inside a thread's 8-edge window -> plain float4 store;
// window-crossing runs -> atomics.
// ---------------------------------------------------------------------------
__global__ __launch_bounds__(256)
void msg_mfma(const float* __restrict__ xw,
              const float* __restrict__ ea,
              const int*   __restrict__ perm,
              const int*   __restrict__ srcs,
              const int*   __restrict__ dsts,
              const unsigned short* __restrict__ WbotT,  // [128][wstride]
              int wstride,
              const float* __restrict__ bias,
              float* __restrict__ aggr)
{
    __shared__ __align__(16) char smem[64 * 132 * 4];   // 33792 B
    unsigned short (*Asm)[72] = (unsigned short(*)[72])smem;            // 9216 B
    unsigned short (*Bsm)[72] = (unsigned short(*)[72])(smem + 9216);   // 18432 B
    float (*Ms)[132] = (float(*)[132])smem;                             // reuse

    const int p0   = blockIdx.x * 64;
    const int t    = threadIdx.x;
    const int wave = t >> 6;
    const int lane = t & 63;
    const int quad = lane >> 4;
    const int l15  = lane & 15;
    const int tx   = t & 31;
    const int ty   = t >> 5;

    // ---- epilogue prefetch: issue all gathers before staging ----
    const int pbase = p0 + ty * 8;
    int sreg[8], dreg[8];
    #pragma unroll
    for (int r = 0; r < 8; ++r) {
        sreg[r] = srcs[pbase + r];
        dreg[r] = dsts[pbase + r];
    }
    const int dprev = (pbase == 0) ? -1 : dsts[pbase - 1];
    const int dnext = (pbase + 8 >= N_EDGES) ? -1 : dsts[pbase + 8];
    float4 xv[8];
    #pragma unroll
    for (int r = 0; r < 8; ++r)
        xv[r] = *(const float4*)(xw + (size_t)sreg[r] * 128 + tx * 4);

    f32x4 acc[8];
    #pragma unroll
    for (int ct = 0; ct < 8; ++ct) acc[ct] = (f32x4)(0.f);

    // ---- A stage: gather ea rows via perm ----
    {
        const int arow  = t >> 2;
        const int acol0 = (t & 3) * 16;
        const int erow  = perm[p0 + arow];
        const float* sp = ea + (size_t)erow * DE + acol0;
        union { unsigned short us[16]; uint4 q[2]; } tmp;
        #pragma unroll
        for (int u = 0; u < 4; ++u) {
            float4 f = *(const float4*)(sp + u * 4);
            tmp.us[u * 4 + 0] = f2bf(f.x);
            tmp.us[u * 4 + 1] = f2bf(f.y);
            tmp.us[u * 4 + 2] = f2bf(f.z);
            tmp.us[u * 4 + 3] = f2bf(f.w);
        }
        *(uint4*)&Asm[arow][acol0]     = tmp.q[0];
        *(uint4*)&Asm[arow][acol0 + 8] = tmp.q[1];
    }
    // ---- B stage ----
    {
        const int brow = t >> 1;
        const int bk   = (t & 1) * 32;
        const unsigned short* bp = WbotT + (size_t)brow * wstride + bk;
        uint4 b0 = *(const uint4*)(bp);
        uint4 b1 = *(const uint4*)(bp + 8);
        uint4 b2 = *(const uint4*)(bp + 16);
        uint4 b3 = *(const uint4*)(bp + 24);
        *(uint4*)&Bsm[brow][bk]      = b0;
        *(uint4*)&Bsm[brow][bk + 8]  = b1;
        *(uint4*)&Bsm[brow][bk + 16] = b2;
        *(uint4*)&Bsm[brow][bk + 24] = b3;
    }
    __syncthreads();
    #pragma unroll
    for (int kh = 0; kh < 2; ++kh) {
        bf16x8 a = *(const bf16x8*)&Asm[wave * 16 + l15][kh * 32 + quad * 8];
        #pragma unroll
        for (int ct = 0; ct < 8; ++ct) {
            bf16x8 b = *(const bf16x8*)&Bsm[ct * 16 + l15][kh * 32 + quad * 8];
            acc[ct] = __builtin_amdgcn_mfma_f32_16x16x32_bf16(a, b, acc[ct], 0, 0, 0);
        }
    }
    __syncthreads();

    // ---- acc -> Ms (edge-major fp32) ----
    #pragma unroll
    for (int ct = 0; ct < 8; ++ct)
        #pragma unroll
        for (int reg = 0; reg < 4; ++reg)
            Ms[wave * 16 + quad * 4 + reg][ct * 16 + l15] = acc[ct][reg];
    __syncthreads();

    // ---- run-compressed scatter: plain store for complete runs ----
    float bv[4];
    *(float4*)bv = *(const float4*)(bias + tx * 4);

    int run_d = dreg[0];
    bool first = true;
    float run[4];
    {
        #pragma unroll
        for (int c = 0; c < 4; ++c) {
            float v = Ms[ty * 8][tx * 4 + c] + xv[0][c] + bv[c];
            run[c] = v > 0.f ? v : 0.f;
        }
    }
    #pragma unroll
    for (int r = 1; r < 8; ++r) {
        float v[4];
        #pragma unroll
        for (int c = 0; c < 4; ++c) {
            float w = Ms[ty * 8 + r][tx * 4 + c] + xv[r][c] + bv[c];
            v[c] = w > 0.f ? w : 0.f;
        }
        if (dreg[r] != run_d) {
            float* ap = aggr + (size_t)run_d * 128 + tx * 4;
            const bool need_atomic = first && (run_d == dprev);
            if (need_atomic) {
                #pragma unroll
                for (int c = 0; c < 4; ++c) fatomic(ap + c, run[c]);
            } else {
                float4 o; o.x = run[0]; o.y = run[1]; o.z = run[2]; o.w = run[3];
                *(float4*)ap = o;
            }
            first = false;
            run_d = dreg[r];
            #pragma unroll
            for (int c = 0; c < 4; ++c) run[c] = v[c];
        } else {
            #pragma unroll
            for (int c = 0; c < 4; ++c) run[c] += v[c];
        }
    }
    {
        float* ap = aggr + (size_t)run_d * 128 + tx * 4;
        const bool need_atomic = (run_d == dnext) || (first && (run_d == dprev));
        if (need_atomic) {
            #pragma unroll
            for (int c = 0; c < 4; ++c) fatomic(ap + c, run[c]);
        } else {
            float4 o; o.x = run[0]; o.y = run[1]; o.z = run[2]; o.w = run[3];
            *(float4*)ap = o;
        }
    }
}

// ---------------------------------------------------------------------------
extern "C" void kernel_launch(void* const* d_in, const int* in_sizes, int n_in,
                              void* d_out, int out_size, void* d_ws, size_t ws_size,
                              hipStream_t stream) {
    const float* x    = (const float*)d_in[0];
    const int*   eidx = (const int*)  d_in[1];
    const float* ea   = (const float*)d_in[2];
    const float* Wm1  = (const float*)d_in[3];
    const float* bm1  = (const float*)d_in[4];
    const float* Wa1  = (const float*)d_in[5];
    const float* ba1  = (const float*)d_in[6];
    const float* Wm2  = (const float*)d_in[7];
    const float* bm2  = (const float*)d_in[8];
    const float* Wa2  = (const float*)d_in[9];
    const float* ba2  = (const float*)d_in[10];
    float* out = (float*)d_out;

    const int* src = eidx;
    const int* dst = eidx + N_EDGES;

    const size_t nodeBuf = (size_t)N_NODES * DF;
    float* xw   = (float*)d_ws;
    float* aggr = xw + nodeBuf;
    float* h    = aggr + nodeBuf;
    int*   cursor = (int*)(h + nodeBuf);
    int*   perm   = cursor + N_NODES;
    int*   srcs   = perm + N_EDGES;
    int*   dsts   = srcs + N_EDGES;
    unsigned short* WmT1 = (unsigned short*)(dsts + N_EDGES);  // [128][192]
    unsigned short* WaT1 = WmT1 + 128 * 192;                   // [128][256]
    unsigned short* WmT2 = WaT1 + 128 * 256;
    unsigned short* WaT2 = WmT2 + 128 * 192;
    int* blksum = (int*)(WaT2 + 128 * 256);                    // 256 ints

    const int gN = (N_NODES + 63) / 64;       // 782
    const int gE = N_EDGES / 64;              // 10000
    const int gS = (N_NODES + 255) / 256;     // 196
    dim3 blk(256);

    // ---- weights: transpose + bf16 ----
    wconv_kernel<<<(192 * 128 + 255) / 256, blk, 0, stream>>>(Wm1, WmT1, 192);
    wconv_kernel<<<(256 * 128 + 255) / 256, blk, 0, stream>>>(Wa1, WaT1, 256);
    wconv_kernel<<<(192 * 128 + 255) / 256, blk, 0, stream>>>(Wm2, WmT2, 192);
    wconv_kernel<<<(256 * 128 + 255) / 256, blk, 0, stream>>>(Wa2, WaT2, 256);

    // ---- CSR permutation (shared by both layers) ----
    hipMemsetAsync(dsts, 0, N_NODES * sizeof(int), stream);    // hist scratch
    hist_kernel<<<(N_EDGES + 255) / 256, blk, 0, stream>>>(dst, dsts);
    scan1_kernel<<<gS, blk, 0, stream>>>(dsts, cursor, blksum, N_NODES);
    scan2_kernel<<<1, blk, 0, stream>>>(blksum, gS);
    scan3_kernel<<<gS, blk, 0, stream>>>(cursor, blksum, N_NODES);
    build_kernel<<<(N_EDGES + 255) / 256, blk, 0, stream>>>(
        src, dst, cursor, perm, srcs, dsts);

    // ---- layer 1 ----
    hipMemsetAsync(aggr, 0, nodeBuf * sizeof(float), stream);
    gemm_mfma<DF, 0, false, false><<<gN, blk, 0, stream>>>(
        x, nullptr, WmT1, 192, nullptr, xw, N_NODES);
    msg_mfma<<<gE, blk, 0, stream>>>(
        xw, ea, perm, srcs, dsts, WmT1 + 128, 192, bm1, aggr);
    gemm_mfma<DF, DF, true, true><<<gN, blk, 0, stream>>>(
        aggr, x, WaT1, 256, ba1, h, N_NODES);

    // ---- layer 2 ----
    hipMemsetAsync(aggr, 0, nodeBuf * sizeof(float), stream);
    gemm_mfma<DF, 0, false, false><<<gN, blk, 0, stream>>>(
        h, nullptr, WmT2, 192, nullptr, xw, N_NODES);
    msg_mfma<<<gE, blk, 0, stream>>>(
        xw, ea, perm, srcs, dsts, WmT2 + 128, 192, bm2, aggr);
    gemm_mfma<DF, DF, true, true><<<gN, blk, 0, stream>>>(
        aggr, h, WaT2, 256, ba2, out, N_NODES);
}

// Round 6
// 648.982 us; speedup vs baseline: 3.9507x; 1.3020x over previous
//
#include <hip/hip_runtime.h>

// TxGNN R6: kill the epilogue atomics + random ea gather.
// - msg epilogue: block-wide LDS segment-reduce over the 64 sorted rows;
//   interior runs -> plain float4 stores (exclusive ownership by ascending
//   sort), only block-boundary runs -> atomics (15.9M -> ~2.5M).
// - ea pre-sorted+bf16 once (ea_s), reused by both layers: msg A-stage is a
//   coalesced stream, no perm hop, no f2bf in the hot kernel.
// - xw stored bf16: halves the random xw[src] gather bytes.

constexpr int N_NODES = 50000;
constexpr int N_EDGES = 640000;
constexpr int DF = 128;
constexpr int DE = 64;

typedef short bf16x8 __attribute__((ext_vector_type(8)));
typedef float f32x4 __attribute__((ext_vector_type(4)));

__device__ __forceinline__ void fatomic(float* p, float v) {
#if defined(__AMDGCN__)
    unsafeAtomicAdd(p, v);
#else
    atomicAdd(p, v);
#endif
}

__device__ __forceinline__ unsigned short f2bf(float f) {
    union { float f; unsigned u; } v; v.f = f;
    unsigned r = (v.u + 0x7FFFu + ((v.u >> 16) & 1u)) >> 16;
    return (unsigned short)r;
}
__device__ __forceinline__ float b2f(unsigned short u) {
    union { unsigned u; float f; } v; v.u = (unsigned)u << 16;
    return v.f;
}

// ---------------------------------------------------------------------------
__global__ __launch_bounds__(256)
void wconv_kernel(const float* __restrict__ W, unsigned short* __restrict__ WT, int K) {
    int i = blockIdx.x * blockDim.x + threadIdx.x;
    if (i < K * 128) {
        int k = i >> 7, n = i & 127;
        WT[n * K + k] = f2bf(W[k * 128 + n]);
    }
}

// CSR build: histogram -> 3-kernel scan -> permutation scatter.
__global__ __launch_bounds__(256)
void hist_kernel(const int* __restrict__ dst, int* __restrict__ hist) {
    int i = blockIdx.x * blockDim.x + threadIdx.x;
    if (i < N_EDGES) atomicAdd(&hist[dst[i]], 1);
}

__global__ __launch_bounds__(256)
void scan1_kernel(const int* __restrict__ hist, int* __restrict__ excl,
                  int* __restrict__ blksum, int n) {
    __shared__ int buf[256];
    const int t = threadIdx.x;
    const int i = blockIdx.x * 256 + t;
    int v = (i < n) ? hist[i] : 0;
    buf[t] = v;
    __syncthreads();
    #pragma unroll
    for (int off = 1; off < 256; off <<= 1) {
        int x = (t >= off) ? buf[t - off] : 0;
        __syncthreads();
        buf[t] += x;
        __syncthreads();
    }
    if (i < n) excl[i] = buf[t] - v;
    if (t == 255) blksum[blockIdx.x] = buf[255];
}

__global__ __launch_bounds__(256)
void scan2_kernel(int* __restrict__ blksum, int nb) {
    __shared__ int buf[256];
    const int t = threadIdx.x;
    int v = (t < nb) ? blksum[t] : 0;
    buf[t] = v;
    __syncthreads();
    #pragma unroll
    for (int off = 1; off < 256; off <<= 1) {
        int x = (t >= off) ? buf[t - off] : 0;
        __syncthreads();
        buf[t] += x;
        __syncthreads();
    }
    if (t < nb) blksum[t] = buf[t] - v;
}

__global__ __launch_bounds__(256)
void scan3_kernel(int* __restrict__ excl, const int* __restrict__ blksum, int n) {
    const int i = blockIdx.x * 256 + threadIdx.x;
    if (i < n) excl[i] += blksum[blockIdx.x];
}

__global__ __launch_bounds__(256)
void build_kernel(const int* __restrict__ src, const int* __restrict__ dst,
                  int* __restrict__ cursor,
                  int* __restrict__ perm, int* __restrict__ srcs,
                  int* __restrict__ dsts) {
    int e = blockIdx.x * blockDim.x + threadIdx.x;
    if (e < N_EDGES) {
        const int d = dst[e];
        const int pos = atomicAdd(&cursor[d], 1);
        perm[pos] = e;
        srcs[pos] = src[e];
        dsts[pos] = d;
    }
}

// ea_s[p] = bf16(ea[perm[p]]) — sorted, streaming-friendly, reused 2x.
__global__ __launch_bounds__(256)
void ea_sort_kernel(const float* __restrict__ ea, const int* __restrict__ perm,
                    unsigned short* __restrict__ ea_s) {
    const int t = threadIdx.x;
    const int p = blockIdx.x * 16 + (t >> 4);
    const int c = (t & 15) * 4;
    const int e = perm[p];
    float4 f = *(const float4*)(ea + (size_t)e * DE + c);
    ushort4 o;
    o.x = f2bf(f.x); o.y = f2bf(f.y); o.z = f2bf(f.z); o.w = f2bf(f.w);
    *(ushort4*)(ea_s + (size_t)p * DE + c) = o;
}

// ---------------------------------------------------------------------------
// MFMA row GEMM: C[i,:] = act( cat(A1[i],A2[i]) @ W + bias ), N=128 wide.
// OUTBF: write bf16 (for xw) else fp32.
// ---------------------------------------------------------------------------
template<int K1, int K2, bool RELU, bool BIAS, bool OUTBF>
__global__ __launch_bounds__(256)
void gemm_mfma(const float* __restrict__ A1,
               const float* __restrict__ A2,
               const unsigned short* __restrict__ WT, int wstride,
               const float* __restrict__ bias,
               void* __restrict__ Cv, int n)
{
    constexpr int K = K1 + K2;
    __shared__ unsigned short Asm[64][72];
    __shared__ unsigned short Bsm[128][72];

    const int r0   = blockIdx.x * 64;
    const int t    = threadIdx.x;
    const int wave = t >> 6;
    const int lane = t & 63;
    const int quad = lane >> 4;
    const int l15  = lane & 15;

    f32x4 acc[8];
    #pragma unroll
    for (int ct = 0; ct < 8; ++ct) acc[ct] = (f32x4)(0.f);

    const int arow  = t >> 2;
    const int acol0 = (t & 3) * 16;
    int arowg = r0 + arow; if (arowg >= n) arowg = n - 1;
    const int brow = t >> 1;
    const int bk   = (t & 1) * 32;

    for (int k0 = 0; k0 < K; k0 += 64) {
        {
            const int col = k0 + acol0;
            const float* sp = (K2 == 0 || col < K1)
                ? A1 + (size_t)arowg * K1 + col
                : A2 + (size_t)arowg * K2 + (col - K1);
            union { unsigned short us[16]; uint4 q[2]; } tmp;
            #pragma unroll
            for (int u = 0; u < 4; ++u) {
                float4 f = *(const float4*)(sp + u * 4);
                tmp.us[u * 4 + 0] = f2bf(f.x);
                tmp.us[u * 4 + 1] = f2bf(f.y);
                tmp.us[u * 4 + 2] = f2bf(f.z);
                tmp.us[u * 4 + 3] = f2bf(f.w);
            }
            *(uint4*)&Asm[arow][acol0]     = tmp.q[0];
            *(uint4*)&Asm[arow][acol0 + 8] = tmp.q[1];
        }
        {
            const unsigned short* bp = WT + (size_t)brow * wstride + k0 + bk;
            uint4 b0 = *(const uint4*)(bp);
            uint4 b1 = *(const uint4*)(bp + 8);
            uint4 b2 = *(const uint4*)(bp + 16);
            uint4 b3 = *(const uint4*)(bp + 24);
            *(uint4*)&Bsm[brow][bk]      = b0;
            *(uint4*)&Bsm[brow][bk + 8]  = b1;
            *(uint4*)&Bsm[brow][bk + 16] = b2;
            *(uint4*)&Bsm[brow][bk + 24] = b3;
        }
        __syncthreads();
        #pragma unroll
        for (int kh = 0; kh < 2; ++kh) {
            bf16x8 a = *(const bf16x8*)&Asm[wave * 16 + l15][kh * 32 + quad * 8];
            #pragma unroll
            for (int ct = 0; ct < 8; ++ct) {
                bf16x8 b = *(const bf16x8*)&Bsm[ct * 16 + l15][kh * 32 + quad * 8];
                acc[ct] = __builtin_amdgcn_mfma_f32_16x16x32_bf16(a, b, acc[ct], 0, 0, 0);
            }
        }
        __syncthreads();
    }

    #pragma unroll
    for (int ct = 0; ct < 8; ++ct) {
        const int col = ct * 16 + l15;
        const float bval = BIAS ? bias[col] : 0.f;
        #pragma unroll
        for (int reg = 0; reg < 4; ++reg) {
            const int row = r0 + wave * 16 + quad * 4 + reg;
            if (row < n) {
                float v = acc[ct][reg] + bval;
                if (RELU) v = v > 0.f ? v : 0.f;
                if (OUTBF) ((unsigned short*)Cv)[(size_t)row * 128 + col] = f2bf(v);
                else       ((float*)Cv)[(size_t)row * 128 + col] = v;
            }
        }
    }
}

// ---------------------------------------------------------------------------
// Edge message (MFMA) + block-wide LDS segment-reduce scatter.
//   m[p] = relu( xw[srcs[p]] + ea_s[p] @ Wbot + bias ); aggr[dsts[p]] += m
// After MFMA, Ms[64][128] holds messages; xv+bias+relu added in place; wave 0
// scans the 64 dst-sorted rows per 4-col group, reducing runs in registers.
// Interior runs: exclusive ownership (ascending sort) -> plain float4 store.
// Block-boundary runs -> atomics.
// ---------------------------------------------------------------------------
__global__ __launch_bounds__(256)
void msg_mfma(const unsigned short* __restrict__ xwb,   // [N,128] bf16
              const unsigned short* __restrict__ ea_s,  // [E,64] bf16 sorted
              const int*   __restrict__ srcs,
              const int*   __restrict__ dsts,
              const unsigned short* __restrict__ WbotT, // [128][wstride]
              int wstride,
              const float* __restrict__ bias,
              float* __restrict__ aggr)
{
    __shared__ __align__(16) char smem[64 * 132 * 4];   // 33792 B
    unsigned short (*Asm)[72] = (unsigned short(*)[72])smem;            // 9216
    unsigned short (*Bsm)[72] = (unsigned short(*)[72])(smem + 9216);   // 18432
    float (*Ms)[132] = (float(*)[132])smem;                             // alias
    __shared__ int Ds[64];

    const int p0   = blockIdx.x * 64;
    const int t    = threadIdx.x;
    const int wave = t >> 6;
    const int lane = t & 63;
    const int quad = lane >> 4;
    const int l15  = lane & 15;
    const int tx   = t & 31;
    const int ty   = t >> 5;

    if (t < 64) Ds[t] = dsts[p0 + t];

    // ---- prefetch xw[src] rows (bf16, 8B/thread/row, coalesced 256B) ----
    const int pbase = p0 + ty * 8;
    ushort4 xv[8];
    #pragma unroll
    for (int r = 0; r < 8; ++r) {
        const int s = srcs[pbase + r];
        xv[r] = *(const ushort4*)(xwb + (size_t)s * 128 + tx * 4);
    }

    f32x4 acc[8];
    #pragma unroll
    for (int ct = 0; ct < 8; ++ct) acc[ct] = (f32x4)(0.f);

    // ---- A stage: streaming bf16 (no gather, no convert) ----
    {
        const int arow  = t >> 2;
        const int acol0 = (t & 3) * 16;
        const uint4* sp = (const uint4*)(ea_s + (size_t)(p0 + arow) * DE + acol0);
        uint4 a0 = sp[0], a1 = sp[1];
        *(uint4*)&Asm[arow][acol0]     = a0;
        *(uint4*)&Asm[arow][acol0 + 8] = a1;
    }
    // ---- B stage ----
    {
        const int brow = t >> 1;
        const int bk   = (t & 1) * 32;
        const unsigned short* bp = WbotT + (size_t)brow * wstride + bk;
        uint4 b0 = *(const uint4*)(bp);
        uint4 b1 = *(const uint4*)(bp + 8);
        uint4 b2 = *(const uint4*)(bp + 16);
        uint4 b3 = *(const uint4*)(bp + 24);
        *(uint4*)&Bsm[brow][bk]      = b0;
        *(uint4*)&Bsm[brow][bk + 8]  = b1;
        *(uint4*)&Bsm[brow][bk + 16] = b2;
        *(uint4*)&Bsm[brow][bk + 24] = b3;
    }
    __syncthreads();
    #pragma unroll
    for (int kh = 0; kh < 2; ++kh) {
        bf16x8 a = *(const bf16x8*)&Asm[wave * 16 + l15][kh * 32 + quad * 8];
        #pragma unroll
        for (int ct = 0; ct < 8; ++ct) {
            bf16x8 b = *(const bf16x8*)&Bsm[ct * 16 + l15][kh * 32 + quad * 8];
            acc[ct] = __builtin_amdgcn_mfma_f32_16x16x32_bf16(a, b, acc[ct], 0, 0, 0);
        }
    }
    __syncthreads();

    // ---- acc -> Ms (edge-major fp32) ----
    #pragma unroll
    for (int ct = 0; ct < 8; ++ct)
        #pragma unroll
        for (int reg = 0; reg < 4; ++reg)
            Ms[wave * 16 + quad * 4 + reg][ct * 16 + l15] = acc[ct][reg];
    __syncthreads();

    // ---- add xw + bias, relu, in place ----
    float bv[4];
    *(float4*)bv = *(const float4*)(bias + tx * 4);
    #pragma unroll
    for (int r = 0; r < 8; ++r) {
        float4 m = *(float4*)&Ms[ty * 8 + r][tx * 4];
        float v0 = m.x + b2f(xv[r].x) + bv[0];
        float v1 = m.y + b2f(xv[r].y) + bv[1];
        float v2 = m.z + b2f(xv[r].z) + bv[2];
        float v3 = m.w + b2f(xv[r].w) + bv[3];
        m.x = v0 > 0.f ? v0 : 0.f;
        m.y = v1 > 0.f ? v1 : 0.f;
        m.z = v2 > 0.f ? v2 : 0.f;
        m.w = v3 > 0.f ? v3 : 0.f;
        *(float4*)&Ms[ty * 8 + r][tx * 4] = m;
    }
    __syncthreads();

    // ---- wave-0 segment reduce over 64 sorted rows ----
    if (t < 32) {
        const int dprev = (p0 == 0) ? -1 : dsts[p0 - 1];
        const int dnext = (p0 + 64 >= N_EDGES) ? -1 : dsts[p0 + 64];
        const int g4 = t * 4;

        float4 run = *(float4*)&Ms[0][g4];
        int run_d = Ds[0];
        int run_start = 0;
        for (int r = 1; r < 64; ++r) {
            float4 v = *(float4*)&Ms[r][g4];
            const int d = Ds[r];
            if (d != run_d) {
                float* ap = aggr + (size_t)run_d * 128 + g4;
                if (run_start == 0 && run_d == dprev) {
                    fatomic(ap + 0, run.x); fatomic(ap + 1, run.y);
                    fatomic(ap + 2, run.z); fatomic(ap + 3, run.w);
                } else {
                    *(float4*)ap = run;
                }
                run_d = d; run_start = r; run = v;
            } else {
                run.x += v.x; run.y += v.y; run.z += v.z; run.w += v.w;
            }
        }
        float* ap = aggr + (size_t)run_d * 128 + g4;
        if ((run_d == dnext) || (run_start == 0 && run_d == dprev)) {
            fatomic(ap + 0, run.x); fatomic(ap + 1, run.y);
            fatomic(ap + 2, run.z); fatomic(ap + 3, run.w);
        } else {
            *(float4*)ap = run;
        }
    }
}

// ---------------------------------------------------------------------------
extern "C" void kernel_launch(void* const* d_in, const int* in_sizes, int n_in,
                              void* d_out, int out_size, void* d_ws, size_t ws_size,
                              hipStream_t stream) {
    const float* x    = (const float*)d_in[0];
    const int*   eidx = (const int*)  d_in[1];
    const float* ea   = (const float*)d_in[2];
    const float* Wm1  = (const float*)d_in[3];
    const float* bm1  = (const float*)d_in[4];
    const float* Wa1  = (const float*)d_in[5];
    const float* ba1  = (const float*)d_in[6];
    const float* Wm2  = (const float*)d_in[7];
    const float* bm2  = (const float*)d_in[8];
    const float* Wa2  = (const float*)d_in[9];
    const float* ba2  = (const float*)d_in[10];
    float* out = (float*)d_out;

    const int* src = eidx;
    const int* dst = eidx + N_EDGES;

    const size_t nodeBuf = (size_t)N_NODES * DF;
    float* aggr = (float*)d_ws;                                // 25.6 MB
    unsigned short* xwb  = (unsigned short*)(aggr + nodeBuf);  // 12.8 MB
    unsigned short* ea_s = xwb + nodeBuf;                      // 81.9 MB
    int* cursor = (int*)(ea_s + (size_t)N_EDGES * DE);
    int* perm   = cursor + N_NODES;
    int* srcs   = perm + N_EDGES;
    int* dsts   = srcs + N_EDGES;
    unsigned short* WmT1 = (unsigned short*)(dsts + N_EDGES);  // [128][192]
    unsigned short* WaT1 = WmT1 + 128 * 192;                   // [128][256]
    unsigned short* WmT2 = WaT1 + 128 * 256;
    unsigned short* WaT2 = WmT2 + 128 * 192;
    int* blksum = (int*)(WaT2 + 128 * 256);
    float* h = out;   // layer-1 output scratch lives in d_out (overwritten)

    const int gN = (N_NODES + 63) / 64;       // 782
    const int gE = N_EDGES / 64;              // 10000
    const int gS = (N_NODES + 255) / 256;     // 196
    dim3 blk(256);

    // ---- weights: transpose + bf16 ----
    wconv_kernel<<<(192 * 128 + 255) / 256, blk, 0, stream>>>(Wm1, WmT1, 192);
    wconv_kernel<<<(256 * 128 + 255) / 256, blk, 0, stream>>>(Wa1, WaT1, 256);
    wconv_kernel<<<(192 * 128 + 255) / 256, blk, 0, stream>>>(Wm2, WmT2, 192);
    wconv_kernel<<<(256 * 128 + 255) / 256, blk, 0, stream>>>(Wa2, WaT2, 256);

    // ---- CSR permutation + sorted bf16 edge features ----
    hipMemsetAsync(dsts, 0, N_NODES * sizeof(int), stream);    // hist scratch
    hist_kernel<<<(N_EDGES + 255) / 256, blk, 0, stream>>>(dst, dsts);
    scan1_kernel<<<gS, blk, 0, stream>>>(dsts, cursor, blksum, N_NODES);
    scan2_kernel<<<1, blk, 0, stream>>>(blksum, gS);
    scan3_kernel<<<gS, blk, 0, stream>>>(cursor, blksum, N_NODES);
    build_kernel<<<(N_EDGES + 255) / 256, blk, 0, stream>>>(
        src, dst, cursor, perm, srcs, dsts);
    ea_sort_kernel<<<N_EDGES / 16, blk, 0, stream>>>(ea, perm, ea_s);

    // ---- layer 1 ----
    hipMemsetAsync(aggr, 0, nodeBuf * sizeof(float), stream);
    gemm_mfma<DF, 0, false, false, true><<<gN, blk, 0, stream>>>(
        x, nullptr, WmT1, 192, nullptr, xwb, N_NODES);         // xwb = bf16(x@Wm1_top)
    msg_mfma<<<gE, blk, 0, stream>>>(
        xwb, ea_s, srcs, dsts, WmT1 + 128, 192, bm1, aggr);
    gemm_mfma<DF, DF, true, true, false><<<gN, blk, 0, stream>>>(
        aggr, x, WaT1, 256, ba1, h, N_NODES);

    // ---- layer 2 ----
    hipMemsetAsync(aggr, 0, nodeBuf * sizeof(float), stream);
    gemm_mfma<DF, 0, false, false, true><<<gN, blk, 0, stream>>>(
        h, nullptr, WmT2, 192, nullptr, xwb, N_NODES);
    msg_mfma<<<gE, blk, 0, stream>>>(
        xwb, ea_s, srcs, dsts, WmT2 + 128, 192, bm2, aggr);
    gemm_mfma<DF, DF, true, true, false><<<gN, blk, 0, stream>>>(
        aggr, h, WaT2, 256, ba2, out, N_NODES);
}